// Round 4
// baseline (1604.269 us; speedup 1.0000x reference)
//
#include <hip/hip_runtime.h>
#include <math.h>

#define Bn   16
#define CIN  8
#define NT   20
#define COUT 32
#define HW   4096
#define NTHREADS 256

typedef __attribute__((ext_vector_type(8)))  short bf16x8;
typedef __attribute__((ext_vector_type(16))) float f32x16;
typedef __attribute__((ext_vector_type(4)))  int   int4v;

__device__ inline unsigned short f2bf(float f) {
    unsigned u = __builtin_bit_cast(unsigned, f);
    u += 0x7fffu + ((u >> 16) & 1u);          // round-to-nearest-even
    return (unsigned short)(u >> 16);
}
__device__ inline float bf2f(unsigned short u) {
    return __builtin_bit_cast(float, (unsigned)u << 16);
}
__device__ inline float sigm(float x) {
    return 1.0f / (1.0f + __expf(-x));
}
__device__ inline float tanh_fast(float x) {
    x = fminf(fmaxf(x, -15.0f), 15.0f);
    float e = __expf(2.0f * x);
    return (e - 1.0f) / (e + 1.0f);
}

// Gate-interleaved A-fragment weights (validated in r2/r3):
// fragment row m' = co*4 + g  holds original row (g*32 + co).
__global__ __launch_bounds__(256) void prep_w(const float* __restrict__ W,
                                              unsigned short* __restrict__ Wbf) {
    int idx = blockIdx.x * 256 + threadIdx.x;        // 9*3*2*128*8 = 55296
    if (idx >= 9 * 3 * 2 * 128 * 8) return;
    int e    = idx & 7;
    int m    = (idx >> 3) & 127;
    int half = (idx >> 10) & 1;
    int fk   = idx >> 11;
    int kb   = fk % 3;
    int tap  = fk / 3;
    int ch   = kb * 16 + half * 8 + e;
    int co   = m >> 2;
    int g    = m & 3;
    float v = 0.0f;
    if (ch < 40) v = W[(size_t)((g * 32 + co) * 40 + ch) * 9 + tap];
    Wbf[idx] = f2bf(v);
}

__global__ __launch_bounds__(256) void zero_flags(int* flags) {
    flags[blockIdx.x * 256 + threadIdx.x] = 0;
}

__global__ __launch_bounds__(NTHREADS, 2) void convlstm_persist(
    const float* __restrict__ X,                 // (B, CIN, T, H, W) fp32
    const unsigned short* __restrict__ Wbf,
    const float* __restrict__ bias,              // (128)
    const float* __restrict__ Wci,
    const float* __restrict__ Wcf,
    const float* __restrict__ Wco,
    float* __restrict__ out,                     // (B, COUT, T, H, W)
    unsigned long long* __restrict__ stage,      // [2][B][8][64][64] quads of 4 bf16
    int* __restrict__ flags)                     // [B][32]
{
    // LDS: swizzled input tile 33792 | peephole W bf16 24576 | bias 512
    __shared__ __align__(16) unsigned char smem[33792 + 24576 + 512];
    unsigned short* Wlds = (unsigned short*)(smem + 33792);
    float*          lds_b = (float*)(smem + 33792 + 24576);

    const int tid = threadIdx.x;
    const int pid = blockIdx.x;
    const int b   = pid >> 5;
    // XCD-aware remap: XCD g gets TIs 4g..4g+3 (3/4 of halo exchanges stay on-XCD)
    const int TI  = ((pid & 7) << 2) | ((pid >> 3) & 3);
    const int r0  = TI * 2;

    const int wid  = tid >> 6;
    const int lane = tid & 63;
    const int lm   = lane & 31;
    const int half = lane >> 5;

    // ---- one-time: zero tile (covers halo cells + ch-pad forever), stage Wc*, bias ----
    {
        int4v z = {0, 0, 0, 0};
        for (int i = tid; i < 2112; i += NTHREADS) *(int4v*)(smem + i * 16) = z;
    }
    {
        const float* wsrc[3] = {Wci, Wcf, Wco};
#pragma unroll
        for (int pl = 0; pl < 3; ++pl)
            for (int i = tid; i < 4096; i += NTHREADS) {
                int co = i >> 7, p = i & 127;
                Wlds[pl * 4096 + i] = f2bf(wsrc[pl][(co << 12) + TI * 128 + p]);
            }
        if (tid < 128) lds_b[tid] = bias[tid];
    }

    // ---- A-fragments: loaded ONCE for all 20 steps ----
    bf16x8 Af[27];
#pragma unroll
    for (int f = 0; f < 27; ++f)
        Af[f] = *(const bf16x8*)(Wbf + (size_t)((f * 2 + half) * 128 + wid * 32 + lm) * 8);

    // ---- cell state: lives in registers for all 20 steps ----
    float creg[16];
#pragma unroll
    for (int i = 0; i < 16; ++i) creg[i] = 0.0f;

    const unsigned sel0 = half ? 0x01000504u : 0x05040100u;
    const unsigned sel1 = sel0 + 0x02020202u;
    int* myflag = flags + (b << 5) + TI;

    __syncthreads();

    for (int t = 0; t < NT; ++t) {
        // ---- wait for neighbor h(t-1) ----
        if (t > 0) {
            if (tid < 2) {
                int nti = TI + (tid ? 1 : -1);
                if ((unsigned)nti < 32u) {
                    const int* fp = flags + (b << 5) + nti;
                    while (__hip_atomic_load(fp, __ATOMIC_RELAXED,
                                             __HIP_MEMORY_SCOPE_AGENT) < t)
                        __builtin_amdgcn_s_sleep(1);
                }
            }
            __syncthreads();
            __threadfence();   // agent acquire: invalidate stale cached stage lines
        }

        // ---- fill: wave `wid` fills tile row lr=wid (global row gr), quads q=0..9 ----
        {
            const int  gr    = r0 + wid - 1;
            const bool rok   = (unsigned)gr < 64u;
            const int  lc    = lane + 1;
            const int  cell0 = wid * 33 + (lc >> 1);
            const int  sbase = (lc & 1) << 3;
            const int  sx    = (lc >> 1) & 15;
            const int  pbuf  = (t - 1) & 1;
#pragma unroll
            for (int q = 0; q < 10; ++q) {
                unsigned d0 = 0, d1 = 0;
                if (rok) {
                    if (q < 2) {
                        const float* xp = X + (((size_t)(b * CIN + q * 4) * NT + t) << 12)
                                            + (gr << 6) + lane;
                        float x0 = xp[0];
                        float x1 = xp[(size_t)NT << 12];
                        float x2 = xp[(size_t)(2 * NT) << 12];
                        float x3 = xp[(size_t)(3 * NT) << 12];
                        asm("v_cvt_pk_bf16_f32 %0, %1, %2" : "=v"(d0) : "v"(x0), "v"(x1));
                        asm("v_cvt_pk_bf16_f32 %0, %1, %2" : "=v"(d1) : "v"(x2), "v"(x3));
                    } else if (t > 0) {
                        unsigned long long vv =
                            stage[(((size_t)pbuf * Bn + b) * 8 + (q - 2)) * HW + (gr << 6) + lane];
                        d0 = (unsigned)vv;
                        d1 = (unsigned)(vv >> 32);
                    }
                }
                const int slot = (sbase | (q >> 1)) ^ sx;
                *(unsigned long long*)(smem + cell0 * 256 + slot * 16 + (q & 1) * 8) =
                    ((unsigned long long)d1 << 32) | d0;
            }
        }
        __syncthreads();

        // ---- K loop: 9 taps x 3 k-blocks x 4 n-blocks ----
        f32x16 acc[4];
#pragma unroll
        for (int nb = 0; nb < 4; ++nb)
#pragma unroll
            for (int r = 0; r < 16; ++r) acc[nb][r] = 0.0f;

        __builtin_amdgcn_s_setprio(1);
#pragma unroll
        for (int dy = 0; dy < 3; ++dy)
#pragma unroll
            for (int dx = 0; dx < 3; ++dx)
#pragma unroll
                for (int kb = 0; kb < 3; ++kb) {
                    const int f    = (dy * 3 + dx) * 3 + kb;
                    const int cidx = kb * 2 + half;
#pragma unroll
                    for (int nb = 0; nb < 4; ++nb) {
                        const int lr   = (nb >> 1) + dy;
                        const int lc   = lm + (nb & 1) * 32 + dx;
                        const int slot = (((lc & 1) << 3) + cidx) ^ ((lc >> 1) & 15);
                        const bf16x8 bf =
                            *(const bf16x8*)(smem + (lr * 33 + (lc >> 1)) * 256 + slot * 16);
                        acc[nb] = __builtin_amdgcn_mfma_f32_32x32x16_bf16(Af[f], bf, acc[nb], 0, 0, 0);
                    }
                }
        __builtin_amdgcn_s_setprio(0);

        // ---- in-register LSTM epilogue; c stays in regs; h -> out (fp32) + stage (bf16 quads) ----
#pragma unroll
        for (int nb = 0; nb < 4; ++nb) {
            const int p_loc = nb * 32 + lm;
            const int pos   = TI * 128 + p_loc;
            float hprev = 0.0f;
#pragma unroll
            for (int j = 0; j < 4; ++j) {
                const int co  = wid * 8 + 2 * j + half;
                const int wof = (co << 7) + p_loc;
                const float c0 = creg[nb * 4 + j];
                const float gi = acc[nb][4 * j + 0] + lds_b[co]      + bf2f(Wlds[wof]) * c0;
                const float gf = acc[nb][4 * j + 1] + lds_b[32 + co] + bf2f(Wlds[4096 + wof]) * c0;
                const float gc = acc[nb][4 * j + 2] + lds_b[64 + co];
                const float gq = acc[nb][4 * j + 3] + lds_b[96 + co];

                const float ig = sigm(gi);
                const float fg = sigm(gf);
                const float cn = fg * c0 + ig * tanh_fast(gc);
                const float og = sigm(gq + bf2f(Wlds[2 * 4096 + wof]) * cn);
                const float hn = og * tanh_fast(cn);

                creg[nb * 4 + j] = cn;
                out[(((size_t)(b * COUT + co) * NT + t) << 12) + pos] = hn;

                if (j & 1) {
                    // assemble bf16 quad [co4a..co4a+3] across the half-pair, store 8B
                    unsigned pk;
                    asm("v_cvt_pk_bf16_f32 %0, %1, %2" : "=v"(pk) : "v"(hprev), "v"(hn));
                    unsigned other = (unsigned)__shfl_xor((int)pk, 32, 64);
                    unsigned q0 = __builtin_amdgcn_perm(other, pk, sel0);
                    unsigned q1 = __builtin_amdgcn_perm(other, pk, sel1);
                    const int a = j >> 1;
                    if (half == a) {
                        const int q8  = wid * 2 + a;
                        const int row = r0 + (nb >> 1);
                        stage[(((size_t)(t & 1) * Bn + b) * 8 + q8) * HW + (row << 6)
                              + (nb & 1) * 32 + lm] = ((unsigned long long)q1 << 32) | q0;
                    }
                } else {
                    hprev = hn;
                }
            }
        }

        __syncthreads();            // all waves' stores issued & drained (barrier waits vmcnt 0)
        if (tid == 0) {
            __threadfence();        // agent release: flush local L2 before publishing
            __hip_atomic_store(myflag, t + 1, __ATOMIC_RELEASE, __HIP_MEMORY_SCOPE_AGENT);
        }
    }
}

extern "C" void kernel_launch(void* const* d_in, const int* in_sizes, int n_in,
                              void* d_out, int out_size, void* d_ws, size_t ws_size,
                              hipStream_t stream) {
    const float* X    = (const float*)d_in[0];
    const float* Wf   = (const float*)d_in[1];
    const float* bias = (const float*)d_in[2];
    const float* Wci  = (const float*)d_in[3];
    const float* Wcf  = (const float*)d_in[4];
    const float* Wco  = (const float*)d_in[5];
    float* out = (float*)d_out;

    // ws layout: Wbf 110592 | flags 2048 | stage 8388608  (~8.5 MB total)
    unsigned short*     Wbf   = (unsigned short*)d_ws;
    int*                flags = (int*)((char*)d_ws + 110592);
    unsigned long long* stage = (unsigned long long*)((char*)d_ws + 112640);

    prep_w<<<216, 256, 0, stream>>>(Wf, Wbf);
    zero_flags<<<2, 256, 0, stream>>>(flags);
    convlstm_persist<<<Bn * 32, NTHREADS, 0, stream>>>(
        X, Wbf, bias, Wci, Wcf, Wco, out, stage, flags);
}

// Round 6
// 326.993 us; speedup vs baseline: 4.9061x; 4.9061x over previous
//
#include <hip/hip_runtime.h>
#include <math.h>

#define Bn   16
#define CIN  8
#define NT   20
#define COUT 32
#define HW   4096
#define NTHREADS 256

typedef __attribute__((ext_vector_type(8)))  short bf16x8;
typedef __attribute__((ext_vector_type(16))) float f32x16;
typedef __attribute__((ext_vector_type(4)))  int   int4v;

__device__ inline unsigned short f2bf(float f) {
    unsigned u = __builtin_bit_cast(unsigned, f);
    u += 0x7fffu + ((u >> 16) & 1u);          // round-to-nearest-even
    return (unsigned short)(u >> 16);
}
__device__ inline float bf2f(unsigned short u) {
    return __builtin_bit_cast(float, (unsigned)u << 16);
}
__device__ inline float sigm(float x) {
    return 1.0f / (1.0f + __expf(-x));
}
__device__ inline float tanh_fast(float x) {
    x = fminf(fmaxf(x, -15.0f), 15.0f);
    float e = __expf(2.0f * x);
    return (e - 1.0f) / (e + 1.0f);
}

// Gate-interleaved A-fragment weights (validated r2-r4):
// fragment row m' = co*4 + g holds original row (g*32 + co).
__global__ __launch_bounds__(256) void prep_w(const float* __restrict__ W,
                                              unsigned short* __restrict__ Wbf) {
    int idx = blockIdx.x * 256 + threadIdx.x;        // 9*3*2*128*8 = 55296
    if (idx >= 9 * 3 * 2 * 128 * 8) return;
    int e    = idx & 7;
    int m    = (idx >> 3) & 127;
    int half = (idx >> 10) & 1;
    int fk   = idx >> 11;
    int kb   = fk % 3;
    int tap  = fk / 3;
    int ch   = kb * 16 + half * 8 + e;
    int co   = m >> 2;
    int g    = m & 3;
    float v = 0.0f;
    if (ch < 40) v = W[(size_t)((g * 32 + co) * 40 + ch) * 9 + tap];
    Wbf[idx] = f2bf(v);
}

__global__ __launch_bounds__(256) void zero_flags(int* flags) {
    flags[blockIdx.x * 256 + threadIdx.x] = 0;
}

__global__ __launch_bounds__(NTHREADS, 2) void convlstm_persist(
    const float* __restrict__ X,                 // (B, CIN, T, H, W) fp32
    const unsigned short* __restrict__ Wbf,
    const float* __restrict__ bias,              // (128)
    const float* __restrict__ Wci,
    const float* __restrict__ Wcf,
    const float* __restrict__ Wco,
    float* __restrict__ out,                     // (B, COUT, T, H, W) — write-only
    unsigned long long* __restrict__ stage,      // [2][B][64 rows][8 quads][64 cols] u64
    int* __restrict__ flags)                     // [B][32]
{
    // LDS: swizzled input tile 33792 | peephole W bf16 24576 | bias 512
    __shared__ __align__(16) unsigned char smem[33792 + 24576 + 512];
    unsigned short* Wlds = (unsigned short*)(smem + 33792);
    float*          lds_b = (float*)(smem + 33792 + 24576);

    const int tid = threadIdx.x;
    const int pid = blockIdx.x;
    const int b   = pid >> 5;
    // XCD-aware remap: neighbor TIs land on the same XCD 3/4 of the time
    const int TI  = ((pid & 7) << 2) | ((pid >> 3) & 3);
    const int r0  = TI * 2;

    const int wid  = tid >> 6;
    const int lane = tid & 63;
    const int lm   = lane & 31;
    const int half = lane >> 5;

    // ---- one-time: zero tile (halo rows + ch-pad stay zero forever), Wc*, bias ----
    {
        int4v z = {0, 0, 0, 0};
        for (int i = tid; i < 2112; i += NTHREADS) *(int4v*)(smem + i * 16) = z;
    }
    {
        const float* wsrc[3] = {Wci, Wcf, Wco};
#pragma unroll
        for (int pl = 0; pl < 3; ++pl)
            for (int i = tid; i < 4096; i += NTHREADS) {
                int co = i >> 7, p = i & 127;
                Wlds[pl * 4096 + i] = f2bf(wsrc[pl][(co << 12) + TI * 128 + p]);
            }
        if (tid < 128) lds_b[tid] = bias[tid];
    }

    // ---- A-fragments: loaded ONCE for all 20 steps ----
    bf16x8 Af[27];
#pragma unroll
    for (int f = 0; f < 27; ++f)
        Af[f] = *(const bf16x8*)(Wbf + (size_t)((f * 2 + half) * 128 + wid * 32 + lm) * 8);

    // ---- cell state lives in registers for all 20 steps ----
    float creg[16];
#pragma unroll
    for (int i = 0; i < 16; ++i) creg[i] = 0.0f;

    const unsigned sel0 = half ? 0x01000504u : 0x05040100u;
    const unsigned sel1 = sel0 + 0x02020202u;
    int* myflag = flags + (b << 5) + TI;

    __syncthreads();

    for (int t = 0; t < NT; ++t) {
        // ---- wait for neighbors' h(t-1) (atomic flag only; NO fence) ----
        if (t > 0) {
            if (tid < 2) {
                const int nti = TI + (tid ? 1 : -1);
                if ((unsigned)nti < 32u) {
                    const int* fp = flags + (b << 5) + nti;
                    while (__hip_atomic_load(fp, __ATOMIC_RELAXED,
                                             __HIP_MEMORY_SCOPE_AGENT) < t)
                        __builtin_amdgcn_s_sleep(2);
                }
            }
            __syncthreads();
        }

        // ---- fill: wave `wid` owns tile row lr=wid (global row gr) ----
        {
            const int  gr    = r0 + wid - 1;
            const bool rok   = (unsigned)gr < 64u;
            const int  lc    = lane + 1;
            const int  cell0 = wid * 33 + (lc >> 1);
            const int  sbase = (lc & 1) << 3;
            const int  sx    = (lc >> 1) & 15;

            if (rok) {
                // X channels 0..7 -> one b128 slot (cidx 0)
                const float* xp = X + ((((size_t)b * CIN) * NT + t) << 12)
                                    + (gr << 6) + lane;
                const size_t chs = (size_t)NT << 12;
                float x0 = xp[0],       x1 = xp[chs],     x2 = xp[2 * chs], x3 = xp[3 * chs];
                float x4 = xp[4 * chs], x5 = xp[5 * chs], x6 = xp[6 * chs], x7 = xp[7 * chs];
                unsigned d0, d1, d2, d3;
                asm("v_cvt_pk_bf16_f32 %0, %1, %2" : "=v"(d0) : "v"(x0), "v"(x1));
                asm("v_cvt_pk_bf16_f32 %0, %1, %2" : "=v"(d1) : "v"(x2), "v"(x3));
                asm("v_cvt_pk_bf16_f32 %0, %1, %2" : "=v"(d2) : "v"(x4), "v"(x5));
                asm("v_cvt_pk_bf16_f32 %0, %1, %2" : "=v"(d3) : "v"(x6), "v"(x7));
                int4v xq = {(int)d0, (int)d1, (int)d2, (int)d3};
                *(int4v*)(smem + cell0 * 256 + ((sbase ^ sx) << 4)) = xq;
            }
            // halo rows: wave 0 (row r0-1 from left) / wave 3 (row r0+2 from right)
            const bool need_halo =
                (t > 0) && ((wid == 0 && TI > 0) || (wid == 3 && TI < 31));
            if (need_halo) {
                const unsigned long long* sp =
                    stage + ((((size_t)((t - 1) & 1) * Bn + b) * 64 + gr) << 9) + lane;
#pragma unroll
                for (int qq = 0; qq < 4; ++qq) {
                    unsigned long long v0 = __hip_atomic_load(
                        sp + (2 * qq) * 64, __ATOMIC_RELAXED, __HIP_MEMORY_SCOPE_AGENT);
                    unsigned long long v1 = __hip_atomic_load(
                        sp + (2 * qq + 1) * 64, __ATOMIC_RELAXED, __HIP_MEMORY_SCOPE_AGENT);
                    const int slot = (sbase | (qq + 1)) ^ sx;
                    int4v hv = {(int)(unsigned)v0, (int)(v0 >> 32),
                                (int)(unsigned)v1, (int)(v1 >> 32)};
                    *(int4v*)(smem + cell0 * 256 + (slot << 4)) = hv;
                }
            }
        }
        __syncthreads();

        // ---- K loop: 9 taps x 3 k-blocks x 4 n-blocks ----
        f32x16 acc[4];
#pragma unroll
        for (int nb = 0; nb < 4; ++nb)
#pragma unroll
            for (int r = 0; r < 16; ++r) acc[nb][r] = 0.0f;

        __builtin_amdgcn_s_setprio(1);
#pragma unroll
        for (int dy = 0; dy < 3; ++dy)
#pragma unroll
            for (int dx = 0; dx < 3; ++dx)
#pragma unroll
                for (int kb = 0; kb < 3; ++kb) {
                    const int f    = (dy * 3 + dx) * 3 + kb;
                    const int cidx = kb * 2 + half;
#pragma unroll
                    for (int nb = 0; nb < 4; ++nb) {
                        const int lr   = (nb >> 1) + dy;
                        const int lc   = lm + (nb & 1) * 32 + dx;
                        const int slot = (((lc & 1) << 3) + cidx) ^ ((lc >> 1) & 15);
                        const bf16x8 bf =
                            *(const bf16x8*)(smem + (lr * 33 + (lc >> 1)) * 256 + slot * 16);
                        acc[nb] = __builtin_amdgcn_mfma_f32_32x32x16_bf16(Af[f], bf, acc[nb], 0, 0, 0);
                    }
                }
        __builtin_amdgcn_s_setprio(0);

        __syncthreads();   // tile reads done before epilogue rewrites h slots

        // ---- in-register LSTM epilogue; h -> out + own LDS tile + halo stage ----
#pragma unroll
        for (int nb = 0; nb < 4; ++nb) {
            const int p_loc = nb * 32 + lm;          // 0..127 over the 2-row span
            const int pos   = TI * 128 + p_loc;
            const int col   = (nb & 1) * 32 + lm;    // 0..63 column within the row  (r5 BUG FIX)
            const int lc    = col + 1;
            const int cell  = (1 + (nb >> 1)) * 33 + (lc >> 1);
            const int sbase = (lc & 1) << 3;
            const int sx    = (lc >> 1) & 15;
            const int row   = r0 + (nb >> 1);
            const bool hstore = (nb >> 1) ? (TI < 31) : (TI > 0);
            float hprev = 0.0f;
#pragma unroll
            for (int j = 0; j < 4; ++j) {
                const int co  = wid * 8 + 2 * j + half;
                const int wof = (co << 7) + p_loc;
                const float c0 = creg[nb * 4 + j];
                const float gi = acc[nb][4 * j + 0] + lds_b[co]      + bf2f(Wlds[wof]) * c0;
                const float gf = acc[nb][4 * j + 1] + lds_b[32 + co] + bf2f(Wlds[4096 + wof]) * c0;
                const float gc = acc[nb][4 * j + 2] + lds_b[64 + co];
                const float gq = acc[nb][4 * j + 3] + lds_b[96 + co];

                const float ig = sigm(gi);
                const float fg = sigm(gf);
                const float cn = fg * c0 + ig * tanh_fast(gc);
                const float og = sigm(gq + bf2f(Wlds[2 * 4096 + wof]) * cn);
                const float hn = og * tanh_fast(cn);

                creg[nb * 4 + j] = cn;
                out[(((size_t)(b * COUT + co) * NT + t) << 12) + pos] = hn;

                if (j & 1) {
                    unsigned pk;
                    asm("v_cvt_pk_bf16_f32 %0, %1, %2" : "=v"(pk) : "v"(hprev), "v"(hn));
                    unsigned other = (unsigned)__shfl_xor((int)pk, 32, 64);
                    unsigned q0 = __builtin_amdgcn_perm(other, pk, sel0);
                    unsigned q1 = __builtin_amdgcn_perm(other, pk, sel1);
                    const int a = j >> 1;
                    if (half == a) {
                        const int q8 = wid * 2 + a;
                        const unsigned long long quad =
                            ((unsigned long long)q1 << 32) | q0;
                        // own tile, rows 1..2, quad tq = 2+q8 (next step's B operand)
                        const int tq = 2 + q8;
                        *(unsigned long long*)(smem + cell * 256 +
                            (((sbase | (tq >> 1)) ^ sx) << 4) + ((tq & 1) << 3)) = quad;
                        if (hstore)
                            __hip_atomic_store(
                                stage + ((((size_t)(t & 1) * Bn + b) * 64 + row) << 9)
                                      + (q8 << 6) + col,
                                quad, __ATOMIC_RELAXED, __HIP_MEMORY_SCOPE_AGENT);
                    }
                } else {
                    hprev = hn;
                }
            }
        }

        __syncthreads();   // per-wave vmcnt(0) drain: all halo stores complete
        if (tid == 0)
            __hip_atomic_store(myflag, t + 1, __ATOMIC_RELAXED,
                               __HIP_MEMORY_SCOPE_AGENT);
    }
}

extern "C" void kernel_launch(void* const* d_in, const int* in_sizes, int n_in,
                              void* d_out, int out_size, void* d_ws, size_t ws_size,
                              hipStream_t stream) {
    const float* X    = (const float*)d_in[0];
    const float* Wf   = (const float*)d_in[1];
    const float* bias = (const float*)d_in[2];
    const float* Wci  = (const float*)d_in[3];
    const float* Wcf  = (const float*)d_in[4];
    const float* Wco  = (const float*)d_in[5];
    float* out = (float*)d_out;

    // ws: Wbf 110592 | flags 2048 | stage 8388608  (~8.5 MB)
    unsigned short*     Wbf   = (unsigned short*)d_ws;
    int*                flags = (int*)((char*)d_ws + 110592);
    unsigned long long* stage = (unsigned long long*)((char*)d_ws + 112640);

    prep_w<<<216, 256, 0, stream>>>(Wf, Wbf);
    zero_flags<<<2, 256, 0, stream>>>(flags);
    convlstm_persist<<<Bn * 32, NTHREADS, 0, stream>>>(
        X, Wbf, bias, Wci, Wcf, Wco, out, stage, flags);
}